// Round 1
// baseline (35.485 us; speedup 1.0000x reference)
//
#include <hip/hip_runtime.h>
#include <math.h>

#define H_SIDE 14
#define P 196
#define SLAB 38809   // 197*197
#define BIGL 1000000

__global__ __launch_bounds__(256) void blob_row_kernel(const float* __restrict__ qk,
                                                       float* __restrict__ rowH) {
  const int row = blockIdx.x;
  const int t = threadIdx.x;

  __shared__ float xv[P];     // masked relu values (0 for background)
  __shared__ int   lab[P];
  __shared__ float red[256];
  __shared__ int   changed;

  // ---- load CLS->patch scores: slab row 0, cols 1..196 (contiguous) ----
  float x = 0.0f;
  if (t < P) x = qk[(size_t)row * SLAB + 1 + t];

  // ---- mean over 196 ----
  red[t] = (t < P) ? x : 0.0f;
  __syncthreads();
  for (int s = 128; s > 0; s >>= 1) {
    if (t < s) red[t] += red[t + s];
    __syncthreads();
  }
  const float mean = red[0] * (1.0f / (float)P);

  const bool msk = (t < P) && (x > mean);
  const float v = msk ? (x - mean) + 1e-9f : 0.0f;
  if (t < P) {
    xv[t]  = v;
    lab[t] = msk ? t : BIGL;
  }
  __syncthreads();

  // ---- 8-connected min-label propagation + pointer jumping ----
  const int r0 = t / H_SIDE;
  const int c0 = t % H_SIDE;
  for (;;) {
    if (t == 0) changed = 0;
    __syncthreads();
    int l = BIGL, best = BIGL;
    if (msk) {
      l = lab[t];
      best = l;
      #pragma unroll
      for (int di = -1; di <= 1; ++di) {
        int nr = r0 + di;
        if (nr < 0 || nr >= H_SIDE) continue;
        #pragma unroll
        for (int dj = -1; dj <= 1; ++dj) {
          int nc = c0 + dj;
          if (nc < 0 || nc >= H_SIDE) continue;
          int nl = lab[nr * H_SIDE + nc];   // background = BIGL, ignored by min
          best = best < nl ? best : nl;
        }
      }
      // pointer jump: best is always the index of a mask pixel in this component
      int jl = lab[best];
      best = best < jl ? best : jl;
    }
    __syncthreads();
    if (msk && best < l) { lab[t] = best; changed = 1; }
    __syncthreads();
    if (changed == 0) break;
  }

  // ---- B = sum of masked xv over the row ----
  red[t] = (t < P) ? v : 0.0f;
  __syncthreads();
  for (int s = 128; s > 0; s >>= 1) {
    if (t < s) red[t] += red[t + s];
    __syncthreads();
  }
  const float Bsum = red[0];
  __syncthreads();   // before reusing red

  // ---- per-component sums (deterministic: broadcast LDS scan, no atomics) ----
  float pu = 0.0f;
  if (t < P) {
    for (int q = 0; q < P; ++q) {
      pu += (lab[q] == t) ? xv[q] : 0.0f;   // lab[q]==t implies mask[q]
    }
  }
  float h = 0.0f;
  if (msk && lab[t] == t) {                 // component root <=> valid segment
    float pn = pu / Bsum;
    h = -pn * logf(pn);
  }

  // ---- row entropy sum ----
  red[t] = h;
  __syncthreads();
  for (int s = 128; s > 0; s >>= 1) {
    if (t < s) red[t] += red[t + s];
    __syncthreads();
  }
  if (t == 0) rowH[row] = red[0];
}

__global__ __launch_bounds__(256) void blob_reduce_kernel(const float* __restrict__ rowH,
                                                          float* __restrict__ out, int n) {
  __shared__ float red[256];
  const int t = threadIdx.x;
  float s = 0.0f;
  for (int i = t; i < n; i += 256) s += rowH[i];
  red[t] = s;
  __syncthreads();
  for (int k = 128; k > 0; k >>= 1) {
    if (t < k) red[t] += red[t + k];
    __syncthreads();
  }
  if (t == 0) out[0] = red[0] / (float)n;
}

extern "C" void kernel_launch(void* const* d_in, const int* in_sizes, int n_in,
                              void* d_out, int out_size, void* d_ws, size_t ws_size,
                              hipStream_t stream) {
  const float* qk = (const float*)d_in[0];
  float* out = (float*)d_out;
  float* rowH = (float*)d_ws;

  const int nrows = in_sizes[0] / SLAB;   // 128 * 12 = 1536

  blob_row_kernel<<<nrows, 256, 0, stream>>>(qk, rowH);
  blob_reduce_kernel<<<1, 256, 0, stream>>>(rowH, out, nrows);
}

// Round 2
// 23.588 us; speedup vs baseline: 1.5044x; 1.5044x over previous
//
#include <hip/hip_runtime.h>
#include <math.h>

#define H_SIDE 14
#define P 196
#define SLAB 38809          // 197*197
#define BIGL (1 << 30)
#define ROWS_PER_BLOCK 4    // one wave64 per row

__global__ __launch_bounds__(256) void blob_row_kernel(const float* __restrict__ qk,
                                                       float* __restrict__ rowH,
                                                       int nrows) {
  const int wid  = threadIdx.x >> 6;
  const int lane = threadIdx.x & 63;
  const int row  = blockIdx.x * ROWS_PER_BLOCK + wid;
  if (row >= nrows) return;            // no barriers anywhere -> safe

  // padded 16x16 grid per wave: border = background, interior [1..14]^2
  __shared__ int   lab_s[ROWS_PER_BLOCK][256];
  __shared__ float ps_s [ROWS_PER_BLOCK][256];
  int*   lab = lab_s[wid];
  float* ps  = ps_s[wid];

  // ---- per-lane owned padded cells: pc = lane + 64k, k=0..3 ----
  int   pc_[4], px_[4];
  bool  in_[4];
  float x_[4];
  #pragma unroll
  for (int k = 0; k < 4; ++k) {
    const int pc = lane + 64 * k;
    const int pr = pc >> 4, pcc = pc & 15;
    const bool interior = (pr >= 1) & (pr <= H_SIDE) & (pcc >= 1) & (pcc <= H_SIDE);
    const int p = (pr - 1) * H_SIDE + (pcc - 1);   // flat pixel idx 0..195
    pc_[k] = pc; px_[k] = p; in_[k] = interior;
    x_[k] = interior ? qk[(size_t)row * SLAB + 1 + p] : 0.0f;
  }

  // ---- mean over 196 (wave butterfly, fixed order) ----
  float s = x_[0] + x_[1] + x_[2] + x_[3];
  #pragma unroll
  for (int off = 32; off >= 1; off >>= 1) s += __shfl_xor(s, off);
  const float mean = s * (1.0f / (float)P);

  // ---- mask, xv, init LDS ----
  float v_[4];
  #pragma unroll
  for (int k = 0; k < 4; ++k) {
    const bool msk = in_[k] & (x_[k] > mean);
    v_[k] = msk ? (x_[k] - mean) + 1e-9f : 0.0f;
    lab[pc_[k]] = msk ? pc_[k] : BIGL;   // labels are padded indices (order-preserving)
    ps [pc_[k]] = 0.0f;
  }
  __builtin_amdgcn_wave_barrier();

  // ---- 8-connected min-label propagation + pointer jumping (wave-sync, no barriers) ----
  const int NOFF[8] = {-17, -16, -15, -1, 1, 15, 16, 17};
  for (;;) {
    bool changed = false;
    #pragma unroll
    for (int k = 0; k < 4; ++k) {
      const int pc = pc_[k];
      const int l = lab[pc];
      if (l < BIGL) {                      // masked pixel
        int best = l;
        #pragma unroll
        for (int e = 0; e < 8; ++e) {
          const int nl = lab[pc + NOFF[e]];
          best = best < nl ? best : nl;
        }
        const int jl = lab[best];          // pointer jump (best is a masked cell)
        best = best < jl ? best : jl;
        if (best < l) { lab[pc] = best; changed = true; }
      }
    }
    if (!__any((int)changed)) break;
  }

  // ---- B = sum of masked xv over the row ----
  float b = v_[0] + v_[1] + v_[2] + v_[3];
  #pragma unroll
  for (int off = 32; off >= 1; off >>= 1) b += __shfl_xor(b, off);

  // ---- per-component sums: LDS atomic scatter (wave-lockstep -> deterministic) ----
  #pragma unroll
  for (int k = 0; k < 4; ++k) {
    const int l = lab[pc_[k]];
    if (l < BIGL) atomicAdd(&ps[l], v_[k]);
  }
  __builtin_amdgcn_wave_barrier();

  // ---- entropy at component roots ----
  float h = 0.0f;
  #pragma unroll
  for (int k = 0; k < 4; ++k) {
    if (lab[pc_[k]] == pc_[k]) {           // root <=> masked && label==self
      const float pn = ps[pc_[k]] / b;
      h += -pn * __logf(pn);
    }
  }
  #pragma unroll
  for (int off = 32; off >= 1; off >>= 1) h += __shfl_xor(h, off);

  if (lane == 0) rowH[row] = h;
}

__global__ __launch_bounds__(256) void blob_reduce_kernel(const float* __restrict__ rowH,
                                                          float* __restrict__ out, int n) {
  __shared__ float red[256];
  const int t = threadIdx.x;
  float s = 0.0f;
  for (int i = t; i < n; i += 256) s += rowH[i];
  red[t] = s;
  __syncthreads();
  for (int k = 128; k > 0; k >>= 1) {
    if (t < k) red[t] += red[t + k];
    __syncthreads();
  }
  if (t == 0) out[0] = red[0] / (float)n;
}

extern "C" void kernel_launch(void* const* d_in, const int* in_sizes, int n_in,
                              void* d_out, int out_size, void* d_ws, size_t ws_size,
                              hipStream_t stream) {
  const float* qk = (const float*)d_in[0];
  float* out  = (float*)d_out;
  float* rowH = (float*)d_ws;

  const int nrows = in_sizes[0] / SLAB;   // 1536
  const int nblk  = (nrows + ROWS_PER_BLOCK - 1) / ROWS_PER_BLOCK;

  blob_row_kernel<<<nblk, 256, 0, stream>>>(qk, rowH, nrows);
  blob_reduce_kernel<<<1, 256, 0, stream>>>(rowH, out, nrows);
}